// Round 1
// baseline (14657.382 us; speedup 1.0000x reference)
//
#include <hip/hip_runtime.h>

#define NN 50000
#define DD 256
#define EE 800000
#define RR 5
#define HH 64

// ws layout (floats):
//   [0, RR*NN)                : cnt (int32) -> invcnt (float, in place)
//   [RR*NN, RR*NN+RR*DD)      : g accumulators (sum over edges of x[src]/cnt[dst])
//   [RR*NN+RR*DD, ... +RR)    : w (relation weights)
#define WS_CNT 0
#define WS_G (RR * NN)
#define WS_W (RR * NN + RR * DD)

__global__ __launch_bounds__(256) void deg_kernel(const int* __restrict__ dst,
                                                  int* __restrict__ cnt) {
    int i = blockIdx.x * 256 + threadIdx.x;
    if (i < RR * EE) {
        int r = i / EE;
        atomicAdd(&cnt[r * NN + dst[i]], 1);
    }
}

__global__ __launch_bounds__(256) void invcnt_kernel(float* __restrict__ c) {
    int i = blockIdx.x * 256 + threadIdx.x;
    if (i < RR * NN) {
        int v = ((const int*)c)[i];
        c[i] = (v > 0) ? (1.0f / (float)v) : 0.0f;
    }
}

// Per relation (blockIdx.y), wave-per-edge gather-reduce:
// g[r][d] = sum_e x[src_e][d] * invcnt[r][dst_e]
__global__ __launch_bounds__(256) void g_kernel(const float* __restrict__ x,
                                                const int* __restrict__ src,
                                                const int* __restrict__ dst,
                                                const float* __restrict__ invc,
                                                float* __restrict__ g) {
    const int r = blockIdx.y;
    const int wave = threadIdx.x >> 6;
    const int lane = threadIdx.x & 63;
    const int gw = blockIdx.x * 4 + wave;
    const int nw = gridDim.x * 4;
    const int* __restrict__ srcR = src + r * EE;
    const int* __restrict__ dstR = dst + r * EE;
    const float* __restrict__ invcR = invc + r * NN;

    float4 acc = make_float4(0.f, 0.f, 0.f, 0.f);
    for (int e = gw; e < EE; e += nw) {
        int eu = __builtin_amdgcn_readfirstlane(e);
        int s = srcR[eu];
        int dn = dstR[eu];
        float ic = invcR[dn];
        float4 v = ((const float4*)(x + (size_t)s * DD))[lane];
        acc.x += v.x * ic;
        acc.y += v.y * ic;
        acc.z += v.z * ic;
        acc.w += v.w * ic;
    }
    float* gr = g + r * DD + lane * 4;
    unsafeAtomicAdd(gr + 0, acc.x);
    unsafeAtomicAdd(gr + 1, acc.y);
    unsafeAtomicAdd(gr + 2, acc.z);
    unsafeAtomicAdd(gr + 3, acc.w);
}

// Single wave: g -> Linear(256,64) -> LN -> ReLU -> Linear(64,1) -> sigmoid weights
__global__ __launch_bounds__(64) void mlp_kernel(const float* __restrict__ gsum,
                                                 const float* __restrict__ W1,
                                                 const float* __restrict__ b1,
                                                 const float* __restrict__ gamma,
                                                 const float* __restrict__ beta,
                                                 const float* __restrict__ W2,
                                                 const float* __restrict__ b2,
                                                 const float* __restrict__ attn_bias,
                                                 float* __restrict__ w) {
    const int t = threadIdx.x;  // 0..63
    __shared__ float gs[DD];
    const float invN = 1.0f / (float)NN;
    for (int r = 0; r < RR; ++r) {
        for (int d = t; d < DD; d += 64) gs[d] = gsum[r * DD + d] * invN;
        __syncthreads();
        float h = b1[t];
        for (int d = 0; d < DD; ++d) h += gs[d] * W1[d * HH + t];
        // LayerNorm across the 64 lanes (H == wavefront size)
        float mu = h;
        #pragma unroll
        for (int o = 32; o; o >>= 1) mu += __shfl_xor(mu, o, 64);
        mu *= (1.0f / 64.0f);
        float c = h - mu;
        float var = c * c;
        #pragma unroll
        for (int o = 32; o; o >>= 1) var += __shfl_xor(var, o, 64);
        var *= (1.0f / 64.0f);
        float hn = c * rsqrtf(var + 1e-5f) * gamma[t] + beta[t];
        hn = fmaxf(hn, 0.0f);
        float sc = hn * W2[t];
        #pragma unroll
        for (int o = 32; o; o >>= 1) sc += __shfl_xor(sc, o, 64);
        if (t == 0) {
            float s = sc + b2[0] + attn_bias[r];
            float ww = 2.0f / (1.0f + expf(-s * 0.5f));
            ww = fminf(fmaxf(ww, 0.05f), 2.0f);
            w[r] = ww;
        }
        __syncthreads();
    }
}

// out[dst] += w[r] * invcnt[r][dst] * x[src]
__global__ __launch_bounds__(256) void out_kernel(const float* __restrict__ x,
                                                  const int* __restrict__ src,
                                                  const int* __restrict__ dst,
                                                  const float* __restrict__ invc,
                                                  const float* __restrict__ w,
                                                  float* __restrict__ out) {
    const int r = blockIdx.y;
    const float wr = w[r];
    const int wave = threadIdx.x >> 6;
    const int lane = threadIdx.x & 63;
    const int gw = blockIdx.x * 4 + wave;
    const int nw = gridDim.x * 4;
    const int* __restrict__ srcR = src + r * EE;
    const int* __restrict__ dstR = dst + r * EE;
    const float* __restrict__ invcR = invc + r * NN;

    for (int e = gw; e < EE; e += nw) {
        int eu = __builtin_amdgcn_readfirstlane(e);
        int s = srcR[eu];
        int dn = dstR[eu];
        float coef = wr * invcR[dn];
        float4 v = ((const float4*)(x + (size_t)s * DD))[lane];
        float* o = out + (size_t)dn * DD + lane * 4;
        unsafeAtomicAdd(o + 0, v.x * coef);
        unsafeAtomicAdd(o + 1, v.y * coef);
        unsafeAtomicAdd(o + 2, v.z * coef);
        unsafeAtomicAdd(o + 3, v.w * coef);
    }
}

extern "C" void kernel_launch(void* const* d_in, const int* in_sizes, int n_in,
                              void* d_out, int out_size, void* d_ws, size_t ws_size,
                              hipStream_t stream) {
    const float* x = (const float*)d_in[0];
    const int* src = (const int*)d_in[1];
    const int* dst = (const int*)d_in[2];
    const float* W1 = (const float*)d_in[3];
    const float* b1 = (const float*)d_in[4];
    const float* gamma = (const float*)d_in[5];
    const float* beta = (const float*)d_in[6];
    const float* W2 = (const float*)d_in[7];
    const float* b2 = (const float*)d_in[8];
    const float* attn_bias = (const float*)d_in[9];
    float* out = (float*)d_out;
    float* ws = (float*)d_ws;

    float* cnt = ws + WS_CNT;    // int32 view first, float after invcnt_kernel
    float* g = ws + WS_G;
    float* w = ws + WS_W;

    // zero cnt + g + w in one shot
    hipMemsetAsync(ws, 0, (size_t)(RR * NN + RR * DD + RR) * sizeof(float), stream);
    // zero output (we accumulate atomically into it)
    hipMemsetAsync(d_out, 0, (size_t)NN * DD * sizeof(float), stream);

    deg_kernel<<<dim3((RR * EE + 255) / 256), dim3(256), 0, stream>>>(dst, (int*)cnt);
    invcnt_kernel<<<dim3((RR * NN + 255) / 256), dim3(256), 0, stream>>>(cnt);
    g_kernel<<<dim3(512, RR), dim3(256), 0, stream>>>(x, src, dst, cnt, g);
    mlp_kernel<<<dim3(1), dim3(64), 0, stream>>>(g, W1, b1, gamma, beta, W2, b2,
                                                 attn_bias, w);
    out_kernel<<<dim3(512, RR), dim3(256), 0, stream>>>(x, src, dst, cnt, w, out);
}

// Round 2
// 2286.830 us; speedup vs baseline: 6.4095x; 6.4095x over previous
//
#include <hip/hip_runtime.h>

#define NN 50000
#define DD 256
#define EE 800000
#define RR 5
#define HH 64
#define RN (RR * NN)

// ---- CSR-path ws layout (4-byte units) ----
// [0, RN)              cnt (int) -> invc (float, in place)
// [RN, 2*RN)           off (int)    bucket begin
// [2*RN, 3*RN)         cursor (int) fill cursor; == bucket end after fill
// [3*RN, +1280)        g accumulators (RR*DD floats)
// [.. +8)              w (RR used)
// [.. +8)              global counter (1 used)
// [CSR_ESRC, +RR*EE)   esrc (int): src ids grouped by (r,dst) bucket
#define CSR_OFF   (RN)
#define CSR_CUR   (2 * RN)
#define CSR_G     (3 * RN)
#define CSR_W     (3 * RN + 1280)
#define CSR_CTR   (3 * RN + 1288)
#define CSR_ESRC  (3 * RN + 1296)
#define CSR_TOTAL ((size_t)(CSR_ESRC + RR * EE) * 4)

__global__ __launch_bounds__(256) void deg_kernel(const int* __restrict__ dst,
                                                  int* __restrict__ cnt) {
    int i = blockIdx.x * 256 + threadIdx.x;
    if (i < RR * EE) {
        int r = i / EE;
        atomicAdd(&cnt[r * NN + dst[i]], 1);
    }
}

// off[i] = atomicAdd(total, cnt[i]); cursor[i] = off[i]; invc[i] = 1/cnt[i] (in place)
__global__ __launch_bounds__(256) void off_kernel(float* __restrict__ ws) {
    int i = blockIdx.x * 256 + threadIdx.x;
    if (i < RN) {
        int* cnt = (int*)ws;
        int* off = (int*)ws + CSR_OFF;
        int* cur = (int*)ws + CSR_CUR;
        int* ctr = (int*)ws + CSR_CTR;
        int c = cnt[i];
        int o = atomicAdd(ctr, c);
        off[i] = o;
        cur[i] = o;
        ws[i] = (c > 0) ? (1.0f / (float)c) : 0.0f;  // invc overwrites cnt
    }
}

__global__ __launch_bounds__(256) void fill_kernel(const int* __restrict__ src,
                                                   const int* __restrict__ dst,
                                                   int* __restrict__ cur,
                                                   int* __restrict__ esrc) {
    int i = blockIdx.x * 256 + threadIdx.x;
    if (i < RR * EE) {
        int r = i / EE;
        int slot = atomicAdd(&cur[r * NN + dst[i]], 1);
        esrc[slot] = src[i];
    }
}

// edge-parallel gather-reduce: g[r][d] = sum_e x[src_e][d] * invc[r][dst_e]
__global__ __launch_bounds__(256) void g_kernel(const float* __restrict__ x,
                                                const int* __restrict__ src,
                                                const int* __restrict__ dst,
                                                const float* __restrict__ invc,
                                                float* __restrict__ g) {
    const int r = blockIdx.y;
    const int wave = threadIdx.x >> 6;
    const int lane = threadIdx.x & 63;
    const int gw = blockIdx.x * 4 + wave;
    const int nw = gridDim.x * 4;
    const int* __restrict__ srcR = src + r * EE;
    const int* __restrict__ dstR = dst + r * EE;
    const float* __restrict__ invcR = invc + r * NN;

    float4 acc = make_float4(0.f, 0.f, 0.f, 0.f);
    for (int e = gw; e < EE; e += nw) {
        int eu = __builtin_amdgcn_readfirstlane(e);
        int s = srcR[eu];
        int dn = dstR[eu];
        float ic = invcR[dn];
        float4 v = ((const float4*)(x + (size_t)s * DD))[lane];
        acc.x += v.x * ic;
        acc.y += v.y * ic;
        acc.z += v.z * ic;
        acc.w += v.w * ic;
    }
    float* gr = g + r * DD + lane * 4;
    unsafeAtomicAdd(gr + 0, acc.x);
    unsafeAtomicAdd(gr + 1, acc.y);
    unsafeAtomicAdd(gr + 2, acc.z);
    unsafeAtomicAdd(gr + 3, acc.w);
}

// Single wave: g -> Linear(256,64) -> LN -> ReLU -> Linear(64,1) -> sigmoid weights
__global__ __launch_bounds__(64) void mlp_kernel(const float* __restrict__ gsum,
                                                 const float* __restrict__ W1,
                                                 const float* __restrict__ b1,
                                                 const float* __restrict__ gamma,
                                                 const float* __restrict__ beta,
                                                 const float* __restrict__ W2,
                                                 const float* __restrict__ b2,
                                                 const float* __restrict__ attn_bias,
                                                 float* __restrict__ w) {
    const int t = threadIdx.x;  // 0..63
    __shared__ float gs[DD];
    const float invN = 1.0f / (float)NN;
    for (int r = 0; r < RR; ++r) {
        for (int d = t; d < DD; d += 64) gs[d] = gsum[r * DD + d] * invN;
        __syncthreads();
        float h = b1[t];
        for (int d = 0; d < DD; ++d) h += gs[d] * W1[d * HH + t];
        float mu = h;
        #pragma unroll
        for (int o = 32; o; o >>= 1) mu += __shfl_xor(mu, o, 64);
        mu *= (1.0f / 64.0f);
        float c = h - mu;
        float var = c * c;
        #pragma unroll
        for (int o = 32; o; o >>= 1) var += __shfl_xor(var, o, 64);
        var *= (1.0f / 64.0f);
        float hn = c * rsqrtf(var + 1e-5f) * gamma[t] + beta[t];
        hn = fmaxf(hn, 0.0f);
        float sc = hn * W2[t];
        #pragma unroll
        for (int o = 32; o; o >>= 1) sc += __shfl_xor(sc, o, 64);
        if (t == 0) {
            float s = sc + b2[0] + attn_bias[r];
            float ww = 2.0f / (1.0f + expf(-s * 0.5f));
            ww = fminf(fmaxf(ww, 0.05f), 2.0f);
            w[r] = ww;
        }
        __syncthreads();
    }
}

// Pull pass: one wave per node. out[n] = sum_r w[r]*invc[r][n]*sum_{e in bucket(r,n)} x[esrc[e]]
__global__ __launch_bounds__(256) void out_pull_kernel(const float* __restrict__ x,
                                                       const int* __restrict__ esrc,
                                                       const int* __restrict__ off,
                                                       const int* __restrict__ endv,
                                                       const float* __restrict__ invc,
                                                       const float* __restrict__ w,
                                                       float* __restrict__ out) {
    const int node = blockIdx.x * 4 + (threadIdx.x >> 6);
    if (node >= NN) return;
    const int lane = threadIdx.x & 63;

    float4 acc = make_float4(0.f, 0.f, 0.f, 0.f);
    #pragma unroll
    for (int r = 0; r < RR; ++r) {
        const int idx = r * NN + node;
        const int b = __builtin_amdgcn_readfirstlane(off[idx]);
        const int e_ = __builtin_amdgcn_readfirstlane(endv[idx]);
        const float coef = w[r] * invc[idx];
        float4 t = make_float4(0.f, 0.f, 0.f, 0.f);
        for (int e = b; e < e_; ++e) {
            int s = __builtin_amdgcn_readfirstlane(esrc[e]);
            float4 v = ((const float4*)(x + (size_t)s * DD))[lane];
            t.x += v.x; t.y += v.y; t.z += v.z; t.w += v.w;
        }
        acc.x += coef * t.x;
        acc.y += coef * t.y;
        acc.z += coef * t.z;
        acc.w += coef * t.w;
    }
    ((float4*)(out + (size_t)node * DD))[lane] = acc;
}

// ---- fallback (round-1 scatter path) ----
__global__ __launch_bounds__(256) void out_scatter_kernel(const float* __restrict__ x,
                                                          const int* __restrict__ src,
                                                          const int* __restrict__ dst,
                                                          const float* __restrict__ invc,
                                                          const float* __restrict__ w,
                                                          float* __restrict__ out) {
    const int r = blockIdx.y;
    const float wr = w[r];
    const int wave = threadIdx.x >> 6;
    const int lane = threadIdx.x & 63;
    const int gw = blockIdx.x * 4 + wave;
    const int nw = gridDim.x * 4;
    const int* __restrict__ srcR = src + r * EE;
    const int* __restrict__ dstR = dst + r * EE;
    const float* __restrict__ invcR = invc + r * NN;

    for (int e = gw; e < EE; e += nw) {
        int eu = __builtin_amdgcn_readfirstlane(e);
        int s = srcR[eu];
        int dn = dstR[eu];
        float coef = wr * invcR[dn];
        float4 v = ((const float4*)(x + (size_t)s * DD))[lane];
        float* o = out + (size_t)dn * DD + lane * 4;
        unsafeAtomicAdd(o + 0, v.x * coef);
        unsafeAtomicAdd(o + 1, v.y * coef);
        unsafeAtomicAdd(o + 2, v.z * coef);
        unsafeAtomicAdd(o + 3, v.w * coef);
    }
}

__global__ __launch_bounds__(256) void invcnt_kernel(float* __restrict__ c) {
    int i = blockIdx.x * 256 + threadIdx.x;
    if (i < RN) {
        int v = ((const int*)c)[i];
        c[i] = (v > 0) ? (1.0f / (float)v) : 0.0f;
    }
}

extern "C" void kernel_launch(void* const* d_in, const int* in_sizes, int n_in,
                              void* d_out, int out_size, void* d_ws, size_t ws_size,
                              hipStream_t stream) {
    const float* x = (const float*)d_in[0];
    const int* src = (const int*)d_in[1];
    const int* dst = (const int*)d_in[2];
    const float* W1 = (const float*)d_in[3];
    const float* b1 = (const float*)d_in[4];
    const float* gamma = (const float*)d_in[5];
    const float* beta = (const float*)d_in[6];
    const float* W2 = (const float*)d_in[7];
    const float* b2 = (const float*)d_in[8];
    const float* attn_bias = (const float*)d_in[9];
    float* out = (float*)d_out;
    float* ws = (float*)d_ws;

    if (ws_size >= CSR_TOTAL) {
        // ---- CSR pull path ----
        int* cnt = (int*)ws;
        float* invc = ws;
        int* off = (int*)ws + CSR_OFF;
        int* cur = (int*)ws + CSR_CUR;
        float* g = ws + CSR_G;
        float* w = ws + CSR_W;
        int* esrc = (int*)ws + CSR_ESRC;

        hipMemsetAsync(cnt, 0, (size_t)RN * 4, stream);                 // cnt
        hipMemsetAsync(ws + CSR_G, 0, (size_t)(1296) * 4, stream);      // g, w, counter

        deg_kernel<<<dim3((RR * EE + 255) / 256), 256, 0, stream>>>(dst, cnt);
        off_kernel<<<dim3((RN + 255) / 256), 256, 0, stream>>>(ws);
        fill_kernel<<<dim3((RR * EE + 255) / 256), 256, 0, stream>>>(src, dst, cur, esrc);
        g_kernel<<<dim3(512, RR), 256, 0, stream>>>(x, src, dst, invc, g);
        mlp_kernel<<<1, 64, 0, stream>>>(g, W1, b1, gamma, beta, W2, b2, attn_bias, w);
        out_pull_kernel<<<dim3((NN + 3) / 4), 256, 0, stream>>>(x, esrc, off, cur,
                                                                invc, w, out);
    } else {
        // ---- fallback scatter path ----
        float* cnt = ws;
        float* g = ws + RN;
        float* w = ws + RN + RR * DD;
        hipMemsetAsync(ws, 0, (size_t)(RN + RR * DD + RR) * 4, stream);
        hipMemsetAsync(d_out, 0, (size_t)NN * DD * 4, stream);
        deg_kernel<<<dim3((RR * EE + 255) / 256), 256, 0, stream>>>(dst, (int*)cnt);
        invcnt_kernel<<<dim3((RN + 255) / 256), 256, 0, stream>>>(cnt);
        g_kernel<<<dim3(512, RR), 256, 0, stream>>>(x, src, dst, cnt, g);
        mlp_kernel<<<1, 64, 0, stream>>>(g, W1, b1, gamma, beta, W2, b2, attn_bias, w);
        out_scatter_kernel<<<dim3(512, RR), 256, 0, stream>>>(x, src, dst, cnt, w, out);
    }
}

// Round 4
// 1137.032 us; speedup vs baseline: 12.8909x; 2.0112x over previous
//
#include <hip/hip_runtime.h>

#define NN 50000
#define DD 256
#define EE 800000
#define RR 5
#define HH 64
#define RN (RR * NN)

// ---- full-path ws layout (4-byte words) ----
// [0, RN)        cnt (int) -> invc (float, in place)
// [RN, 2RN)      off (int)
// [2RN, 3RN)     cur (int)  (== bucket end after fill)
// [3RN, 4RN)     c (float)  per-(r,src) coefficient sums
// [4RN, +1280)   g
// +8             w
// +8             ctr
// [ESRC, +RR*EE) esrc (int)
// [XH, +NN*DD/2) xh (bf16 packed, 2/word)
#define F_OFF  (RN)
#define F_CUR  (2 * RN)
#define F_C    (3 * RN)
#define F_G    (4 * RN)
#define F_W    (4 * RN + 1280)
#define F_CTR  (4 * RN + 1288)
#define F_ESRC (4 * RN + 1296)
#define F_XH   (F_ESRC + RR * EE)
#define BYTES_BF16 ((size_t)(F_XH + NN * DD / 2) * 4)
#define BYTES_F32  ((size_t)(F_ESRC + RR * EE) * 4)

// ---- round-2 (19MB) layout ----
#define C2_OFF  (RN)
#define C2_CUR  (2 * RN)
#define C2_G    (3 * RN)
#define C2_W    (3 * RN + 1280)
#define C2_CTR  (3 * RN + 1288)
#define C2_ESRC (3 * RN + 1296)
#define BYTES_CSR2 ((size_t)(C2_ESRC + RR * EE) * 4)

__device__ inline unsigned short bf16rn(float f) {
    unsigned u = __float_as_uint(f);
    unsigned r = u + 0x7FFFu + ((u >> 16) & 1u);
    return (unsigned short)(r >> 16);
}

__global__ __launch_bounds__(256) void deg_kernel(const int* __restrict__ dst,
                                                  int* __restrict__ cnt) {
    int i = blockIdx.x * 256 + threadIdx.x;
    if (i < RR * EE) {
        int r = i / EE;
        atomicAdd(&cnt[r * NN + dst[i]], 1);
    }
}

// off/cur = bucket starts via atomic grab; invc = 1/cnt in place of cnt
__global__ __launch_bounds__(256) void off_kernel(int* cnt, int* __restrict__ off,
                                                  int* __restrict__ cur,
                                                  int* __restrict__ ctr, float* invc) {
    int i = blockIdx.x * 256 + threadIdx.x;
    if (i < RN) {
        int cv = cnt[i];
        int o = atomicAdd(ctr, cv);
        off[i] = o;
        cur[i] = o;
        invc[i] = (cv > 0) ? (1.0f / (float)cv) : 0.0f;
    }
}

// scatter src ids into (r,dst) buckets; optionally accumulate c[r][src] += invc[r][dst]
template <bool WITH_C>
__global__ __launch_bounds__(256) void fill_kernel(const int* __restrict__ src,
                                                   const int* __restrict__ dst,
                                                   int* __restrict__ cur,
                                                   int* __restrict__ esrc,
                                                   const float* __restrict__ invc,
                                                   float* __restrict__ c) {
    int i = blockIdx.x * 256 + threadIdx.x;
    if (i < RR * EE) {
        int r = i / EE;
        int d = dst[i];
        int s = src[i];
        int slot = atomicAdd(&cur[r * NN + d], 1);
        esrc[slot] = s;
        if constexpr (WITH_C) {
            unsafeAtomicAdd(&c[r * NN + s], invc[r * NN + d]);
        }
    }
}

// g[r][d] = sum_s c[r][s] * x[s][d] — reads x exactly once, streaming
__global__ __launch_bounds__(256) void gmat_kernel(const float* __restrict__ x,
                                                   const float* __restrict__ c,
                                                   float* __restrict__ g) {
    const int wave = threadIdx.x >> 6;
    const int lane = threadIdx.x & 63;
    const int gw = blockIdx.x * 4 + wave;
    const int nw = gridDim.x * 4;
    float4 a0 = {0, 0, 0, 0}, a1 = {0, 0, 0, 0}, a2 = {0, 0, 0, 0},
           a3 = {0, 0, 0, 0}, a4 = {0, 0, 0, 0};
    for (int s = gw; s < NN; s += nw) {
        float4 v = ((const float4*)(x + (size_t)s * DD))[lane];
        float c0 = c[0 * NN + s], c1 = c[1 * NN + s], c2 = c[2 * NN + s],
              c3 = c[3 * NN + s], c4 = c[4 * NN + s];
        a0.x += c0 * v.x; a0.y += c0 * v.y; a0.z += c0 * v.z; a0.w += c0 * v.w;
        a1.x += c1 * v.x; a1.y += c1 * v.y; a1.z += c1 * v.z; a1.w += c1 * v.w;
        a2.x += c2 * v.x; a2.y += c2 * v.y; a2.z += c2 * v.z; a2.w += c2 * v.w;
        a3.x += c3 * v.x; a3.y += c3 * v.y; a3.z += c3 * v.z; a3.w += c3 * v.w;
        a4.x += c4 * v.x; a4.y += c4 * v.y; a4.z += c4 * v.z; a4.w += c4 * v.w;
    }
    float4 acc[5] = {a0, a1, a2, a3, a4};
    #pragma unroll
    for (int r = 0; r < RR; ++r) {
        float* gr = g + r * DD + lane * 4;
        unsafeAtomicAdd(gr + 0, acc[r].x);
        unsafeAtomicAdd(gr + 1, acc[r].y);
        unsafeAtomicAdd(gr + 2, acc[r].z);
        unsafeAtomicAdd(gr + 3, acc[r].w);
    }
}

// legacy edge-gather g (19MB fallback path)
__global__ __launch_bounds__(256) void g_kernel(const float* __restrict__ x,
                                                const int* __restrict__ src,
                                                const int* __restrict__ dst,
                                                const float* __restrict__ invc,
                                                float* __restrict__ g) {
    const int r = blockIdx.y;
    const int wave = threadIdx.x >> 6;
    const int lane = threadIdx.x & 63;
    const int gw = blockIdx.x * 4 + wave;
    const int nw = gridDim.x * 4;
    const int* __restrict__ srcR = src + r * EE;
    const int* __restrict__ dstR = dst + r * EE;
    const float* __restrict__ invcR = invc + r * NN;
    float4 acc = {0, 0, 0, 0};
    for (int e = gw; e < EE; e += nw) {
        int eu = __builtin_amdgcn_readfirstlane(e);
        int s = srcR[eu];
        int dn = dstR[eu];
        float ic = invcR[dn];
        float4 v = ((const float4*)(x + (size_t)s * DD))[lane];
        acc.x += v.x * ic; acc.y += v.y * ic; acc.z += v.z * ic; acc.w += v.w * ic;
    }
    float* gr = g + r * DD + lane * 4;
    unsafeAtomicAdd(gr + 0, acc.x);
    unsafeAtomicAdd(gr + 1, acc.y);
    unsafeAtomicAdd(gr + 2, acc.z);
    unsafeAtomicAdd(gr + 3, acc.w);
}

__global__ __launch_bounds__(64) void mlp_kernel(const float* __restrict__ gsum,
                                                 const float* __restrict__ W1,
                                                 const float* __restrict__ b1,
                                                 const float* __restrict__ gamma,
                                                 const float* __restrict__ beta,
                                                 const float* __restrict__ W2,
                                                 const float* __restrict__ b2,
                                                 const float* __restrict__ attn_bias,
                                                 float* __restrict__ w) {
    const int t = threadIdx.x;
    __shared__ float gs[DD];
    const float invN = 1.0f / (float)NN;
    for (int r = 0; r < RR; ++r) {
        for (int d = t; d < DD; d += 64) gs[d] = gsum[r * DD + d] * invN;
        __syncthreads();
        float h = b1[t];
        for (int d = 0; d < DD; ++d) h += gs[d] * W1[d * HH + t];
        float mu = h;
        #pragma unroll
        for (int o = 32; o; o >>= 1) mu += __shfl_xor(mu, o, 64);
        mu *= (1.0f / 64.0f);
        float cc = h - mu;
        float var = cc * cc;
        #pragma unroll
        for (int o = 32; o; o >>= 1) var += __shfl_xor(var, o, 64);
        var *= (1.0f / 64.0f);
        float hn = cc * rsqrtf(var + 1e-5f) * gamma[t] + beta[t];
        hn = fmaxf(hn, 0.0f);
        float sc = hn * W2[t];
        #pragma unroll
        for (int o = 32; o; o >>= 1) sc += __shfl_xor(sc, o, 64);
        if (t == 0) {
            float s = sc + b2[0] + attn_bias[r];
            float ww = 2.0f / (1.0f + expf(-s * 0.5f));
            ww = fminf(fmaxf(ww, 0.05f), 2.0f);
            w[r] = ww;
        }
        __syncthreads();
    }
}

// x (f32) -> bf16 packed table
__global__ __launch_bounds__(256) void xcvt_kernel(const float* __restrict__ x,
                                                   ushort4* __restrict__ xh) {
    int i = blockIdx.x * 256 + threadIdx.x;
    if (i < NN * DD / 4) {
        float4 v = ((const float4*)x)[i];
        ushort4 q;
        q.x = bf16rn(v.x); q.y = bf16rn(v.y); q.z = bf16rn(v.z); q.w = bf16rn(v.w);
        xh[i] = q;
    }
}

template <bool BF16>
__device__ inline float4 loadrow(const float* __restrict__ x,
                                 const ushort4* __restrict__ xh, int s, int lane) {
    if constexpr (BF16) {
        ushort4 q = xh[(size_t)s * (DD / 4) + lane];
        float4 v;
        v.x = __uint_as_float((unsigned)q.x << 16);
        v.y = __uint_as_float((unsigned)q.y << 16);
        v.z = __uint_as_float((unsigned)q.z << 16);
        v.w = __uint_as_float((unsigned)q.w << 16);
        return v;
    } else {
        return ((const float4*)(x + (size_t)s * DD))[lane];
    }
}

// pull pass: one wave per node, edge loop unrolled x4 for MLP
template <bool BF16>
__global__ __launch_bounds__(256) void out_pull_kernel(const float* __restrict__ x,
                                                       const ushort4* __restrict__ xh,
                                                       const int* __restrict__ esrc,
                                                       const int* __restrict__ off,
                                                       const int* __restrict__ endv,
                                                       const float* __restrict__ invc,
                                                       const float* __restrict__ w,
                                                       float* __restrict__ out) {
    const int node = blockIdx.x * 4 + (threadIdx.x >> 6);
    if (node >= NN) return;
    const int lane = threadIdx.x & 63;

    float4 acc = {0, 0, 0, 0};
    #pragma unroll
    for (int r = 0; r < RR; ++r) {
        const int idx = r * NN + node;
        const int b = __builtin_amdgcn_readfirstlane(off[idx]);
        const int e_ = __builtin_amdgcn_readfirstlane(endv[idx]);
        const float coef = w[r] * invc[idx];
        float4 t = {0, 0, 0, 0};
        int e = b;
        for (; e + 4 <= e_; e += 4) {
            int s0 = __builtin_amdgcn_readfirstlane(esrc[e + 0]);
            int s1 = __builtin_amdgcn_readfirstlane(esrc[e + 1]);
            int s2 = __builtin_amdgcn_readfirstlane(esrc[e + 2]);
            int s3 = __builtin_amdgcn_readfirstlane(esrc[e + 3]);
            float4 v0 = loadrow<BF16>(x, xh, s0, lane);
            float4 v1 = loadrow<BF16>(x, xh, s1, lane);
            float4 v2 = loadrow<BF16>(x, xh, s2, lane);
            float4 v3 = loadrow<BF16>(x, xh, s3, lane);
            t.x += (v0.x + v1.x) + (v2.x + v3.x);
            t.y += (v0.y + v1.y) + (v2.y + v3.y);
            t.z += (v0.z + v1.z) + (v2.z + v3.z);
            t.w += (v0.w + v1.w) + (v2.w + v3.w);
        }
        for (; e < e_; ++e) {
            int s = __builtin_amdgcn_readfirstlane(esrc[e]);
            float4 v = loadrow<BF16>(x, xh, s, lane);
            t.x += v.x; t.y += v.y; t.z += v.z; t.w += v.w;
        }
        acc.x += coef * t.x; acc.y += coef * t.y;
        acc.z += coef * t.z; acc.w += coef * t.w;
    }
    ((float4*)(out + (size_t)node * DD))[lane] = acc;
}

// ---- last-resort scatter path ----
__global__ __launch_bounds__(256) void invcnt_kernel(float* __restrict__ c) {
    int i = blockIdx.x * 256 + threadIdx.x;
    if (i < RN) {
        int v = ((const int*)c)[i];
        c[i] = (v > 0) ? (1.0f / (float)v) : 0.0f;
    }
}

__global__ __launch_bounds__(256) void out_scatter_kernel(const float* __restrict__ x,
                                                          const int* __restrict__ src,
                                                          const int* __restrict__ dst,
                                                          const float* __restrict__ invc,
                                                          const float* __restrict__ w,
                                                          float* __restrict__ out) {
    const int r = blockIdx.y;
    const float wr = w[r];
    const int wave = threadIdx.x >> 6;
    const int lane = threadIdx.x & 63;
    const int gw = blockIdx.x * 4 + wave;
    const int nw = gridDim.x * 4;
    const int* __restrict__ srcR = src + r * EE;
    const int* __restrict__ dstR = dst + r * EE;
    const float* __restrict__ invcR = invc + r * NN;
    for (int e = gw; e < EE; e += nw) {
        int eu = __builtin_amdgcn_readfirstlane(e);
        int s = srcR[eu];
        int dn = dstR[eu];
        float coef = wr * invcR[dn];
        float4 v = ((const float4*)(x + (size_t)s * DD))[lane];
        float* o = out + (size_t)dn * DD + lane * 4;
        unsafeAtomicAdd(o + 0, v.x * coef);
        unsafeAtomicAdd(o + 1, v.y * coef);
        unsafeAtomicAdd(o + 2, v.z * coef);
        unsafeAtomicAdd(o + 3, v.w * coef);
    }
}

extern "C" void kernel_launch(void* const* d_in, const int* in_sizes, int n_in,
                              void* d_out, int out_size, void* d_ws, size_t ws_size,
                              hipStream_t stream) {
    const float* x = (const float*)d_in[0];
    const int* src = (const int*)d_in[1];
    const int* dst = (const int*)d_in[2];
    const float* W1 = (const float*)d_in[3];
    const float* b1 = (const float*)d_in[4];
    const float* gamma = (const float*)d_in[5];
    const float* beta = (const float*)d_in[6];
    const float* W2 = (const float*)d_in[7];
    const float* b2 = (const float*)d_in[8];
    const float* attn_bias = (const float*)d_in[9];
    float* out = (float*)d_out;
    float* ws = (float*)d_ws;

    const int EDGE_GRID = (RR * EE + 255) / 256;
    const int RN_GRID = (RN + 255) / 256;

    if (ws_size >= BYTES_F32) {
        // c-based g path; bf16 gather table if space allows
        const bool bf16 = (ws_size >= BYTES_BF16);
        int* cnt = (int*)ws;
        float* invc = ws;
        int* off = (int*)ws + F_OFF;
        int* cur = (int*)ws + F_CUR;
        float* c = ws + F_C;
        float* g = ws + F_G;
        float* w = ws + F_W;
        int* ctr = (int*)ws + F_CTR;
        int* esrc = (int*)ws + F_ESRC;
        ushort4* xh = (ushort4*)((int*)ws + F_XH);

        hipMemsetAsync(cnt, 0, (size_t)RN * 4, stream);
        hipMemsetAsync(c, 0, (size_t)(RN + 1296) * 4, stream);  // c, g, w, ctr

        if (bf16)
            xcvt_kernel<<<(NN * DD / 4 + 255) / 256, 256, 0, stream>>>(x, xh);
        deg_kernel<<<EDGE_GRID, 256, 0, stream>>>(dst, cnt);
        off_kernel<<<RN_GRID, 256, 0, stream>>>(cnt, off, cur, ctr, invc);
        fill_kernel<true><<<EDGE_GRID, 256, 0, stream>>>(src, dst, cur, esrc, invc, c);
        gmat_kernel<<<128, 256, 0, stream>>>(x, c, g);
        mlp_kernel<<<1, 64, 0, stream>>>(g, W1, b1, gamma, beta, W2, b2, attn_bias, w);
        if (bf16)
            out_pull_kernel<true><<<(NN + 3) / 4, 256, 0, stream>>>(x, xh, esrc, off,
                                                                    cur, invc, w, out);
        else
            out_pull_kernel<false><<<(NN + 3) / 4, 256, 0, stream>>>(x, xh, esrc, off,
                                                                     cur, invc, w, out);
    } else if (ws_size >= BYTES_CSR2) {
        // round-2 layout: edge-gather g + f32 pull
        int* cnt = (int*)ws;
        float* invc = ws;
        int* off = (int*)ws + C2_OFF;
        int* cur = (int*)ws + C2_CUR;
        float* g = ws + C2_G;
        float* w = ws + C2_W;
        int* ctr = (int*)ws + C2_CTR;
        int* esrc = (int*)ws + C2_ESRC;

        hipMemsetAsync(cnt, 0, (size_t)RN * 4, stream);
        hipMemsetAsync(g, 0, (size_t)1296 * 4, stream);

        deg_kernel<<<EDGE_GRID, 256, 0, stream>>>(dst, cnt);
        off_kernel<<<RN_GRID, 256, 0, stream>>>(cnt, off, cur, ctr, invc);
        fill_kernel<false><<<EDGE_GRID, 256, 0, stream>>>(src, dst, cur, esrc, invc,
                                                          nullptr);
        g_kernel<<<dim3(512, RR), 256, 0, stream>>>(x, src, dst, invc, g);
        mlp_kernel<<<1, 64, 0, stream>>>(g, W1, b1, gamma, beta, W2, b2, attn_bias, w);
        out_pull_kernel<false><<<(NN + 3) / 4, 256, 0, stream>>>(x, nullptr, esrc, off,
                                                                 cur, invc, w, out);
    } else {
        // scatter fallback
        float* cnt = ws;
        float* g = ws + RN;
        float* w = ws + RN + RR * DD;
        hipMemsetAsync(ws, 0, (size_t)(RN + RR * DD + RR) * 4, stream);
        hipMemsetAsync(d_out, 0, (size_t)NN * DD * 4, stream);
        deg_kernel<<<EDGE_GRID, 256, 0, stream>>>(dst, (int*)cnt);
        invcnt_kernel<<<RN_GRID, 256, 0, stream>>>(cnt);
        g_kernel<<<dim3(512, RR), 256, 0, stream>>>(x, src, dst, cnt, g);
        mlp_kernel<<<1, 64, 0, stream>>>(g, W1, b1, gamma, beta, W2, b2, attn_bias, w);
        out_scatter_kernel<<<dim3(512, RR), 256, 0, stream>>>(x, src, dst, cnt, w, out);
    }
}

// Round 5
// 1090.630 us; speedup vs baseline: 13.4394x; 1.0425x over previous
//
#include <hip/hip_runtime.h>

#define NN 50000
#define DD 256
#define EE 800000
#define RR 5
#define HH 64
#define RN (RR * NN)
#define NBLK ((NN + 255) / 256)

// ---- NEW path ws layout (4-byte words) ----
// [0, RN)        cnt (int, [r*NN+d]) -> invc (float, in place)
// [RN, 2RN)      off (int, [d*5+r])  d-major bucket begins
// [2RN, 3RN)     cur (int, [d*5+r])  fill cursor == bucket end after fill
// [3RN, 4RN)     c (float, [r*NN+s]) per-(r,src) coefficient sums
// [4RN, +1280)   g
// +8             w
// [P_BSUM,+256)  per-block degree sums
// [P_BBASE,+256) exclusive block bases
// [P_ESRC)       esrc (ushort, RR*EE entries = 2M words)
// [P_XH)         xh (bf16 packed, NN*DD/2 words)
#define P_OFF   (RN)
#define P_CUR   (2 * RN)
#define P_C     (3 * RN)
#define P_G     (4 * RN)
#define P_W     (4 * RN + 1280)
#define P_BSUM  (4 * RN + 1288)
#define P_BBASE (4 * RN + 1544)
#define P_ESRC  (4 * RN + 1800)
#define P_XH    (P_ESRC + RR * EE / 2)
#define BYTES_NEW ((size_t)(P_XH + NN * DD / 2) * 4)

// ---- old full-path layout (fallback) ----
#define F_OFF  (RN)
#define F_CUR  (2 * RN)
#define F_C    (3 * RN)
#define F_G    (4 * RN)
#define F_W    (4 * RN + 1280)
#define F_CTR  (4 * RN + 1288)
#define F_ESRC (4 * RN + 1296)
#define F_XH   (F_ESRC + RR * EE)
#define BYTES_BF16 ((size_t)(F_XH + NN * DD / 2) * 4)
#define BYTES_F32  ((size_t)(F_ESRC + RR * EE) * 4)

// ---- round-2 layout (fallback) ----
#define C2_OFF  (RN)
#define C2_CUR  (2 * RN)
#define C2_G    (3 * RN)
#define C2_W    (3 * RN + 1280)
#define C2_CTR  (3 * RN + 1288)
#define C2_ESRC (3 * RN + 1296)
#define BYTES_CSR2 ((size_t)(C2_ESRC + RR * EE) * 4)

__device__ inline unsigned short bf16rn(float f) {
    unsigned u = __float_as_uint(f);
    unsigned r = u + 0x7FFFu + ((u >> 16) & 1u);
    return (unsigned short)(r >> 16);
}

__global__ __launch_bounds__(256) void deg_kernel(const int* __restrict__ dst,
                                                  int* __restrict__ cnt) {
    int i = blockIdx.x * 256 + threadIdx.x;
    if (i < RR * EE) {
        int r = i / EE;
        atomicAdd(&cnt[r * NN + dst[i]], 1);
    }
}

// ---- NEW path: deterministic d-major prefix offsets ----
__global__ __launch_bounds__(256) void bsum_kernel(const int* __restrict__ cnt,
                                                   int* __restrict__ bsum) {
    __shared__ int sh[256];
    const int t = threadIdx.x;
    const int d = blockIdx.x * 256 + t;
    int tot = 0;
    if (d < NN) {
        #pragma unroll
        for (int r = 0; r < RR; ++r) tot += cnt[r * NN + d];
    }
    sh[t] = tot;
    __syncthreads();
    for (int o = 128; o; o >>= 1) {
        if (t < o) sh[t] += sh[t + o];
        __syncthreads();
    }
    if (t == 0) bsum[blockIdx.x] = sh[0];
}

__global__ void bscan_kernel(const int* __restrict__ bsum, int* __restrict__ bbase) {
    if (threadIdx.x == 0) {
        int acc = 0;
        for (int b = 0; b < NBLK; ++b) {
            bbase[b] = acc;
            acc += bsum[b];
        }
    }
}

// per-d exclusive offsets via block scan; writes off/cur (d-major) and invc in place of cnt
__global__ __launch_bounds__(256) void off2_kernel(int* __restrict__ cnt_invc,
                                                   const int* __restrict__ bbase,
                                                   int* __restrict__ off,
                                                   int* __restrict__ cur) {
    __shared__ int sh[256];
    const int t = threadIdx.x;
    const int d = blockIdx.x * 256 + t;
    int cc[RR];
    int tot = 0;
    if (d < NN) {
        #pragma unroll
        for (int r = 0; r < RR; ++r) {
            cc[r] = cnt_invc[r * NN + d];
            tot += cc[r];
        }
    }
    sh[t] = tot;
    __syncthreads();
    // Hillis-Steele inclusive scan over the block
    for (int o = 1; o < 256; o <<= 1) {
        int v = (t >= o) ? sh[t - o] : 0;
        __syncthreads();
        sh[t] += v;
        __syncthreads();
    }
    if (d < NN) {
        int base = bbase[blockIdx.x] + sh[t] - tot;  // exclusive prefix
        float* invc = (float*)cnt_invc;
        #pragma unroll
        for (int r = 0; r < RR; ++r) {
            off[d * RR + r] = base;
            cur[d * RR + r] = base;
            base += cc[r];
            invc[r * NN + d] = (cc[r] > 0) ? (1.0f / (float)cc[r]) : 0.0f;
        }
    }
}

// dst-range-blocked fill: scatter ushort src ids into contiguous d-major buckets,
// fused c[r][src] += invc[r][dst]
__global__ __launch_bounds__(256) void fill2_kernel(const int* __restrict__ src,
                                                    const int* __restrict__ dst,
                                                    int* __restrict__ cur,
                                                    unsigned short* __restrict__ esrc,
                                                    const float* __restrict__ invc,
                                                    float* __restrict__ c,
                                                    int dlo, int dhi) {
    int i = blockIdx.x * 256 + threadIdx.x;
    if (i < RR * EE) {
        int d = dst[i];
        if (d >= dlo && d < dhi) {
            int r = i / EE;
            int s = src[i];
            int slot = atomicAdd(&cur[d * RR + r], 1);
            esrc[slot] = (unsigned short)s;
            unsafeAtomicAdd(&c[r * NN + s], invc[r * NN + d]);
        }
    }
}

// g[r][d] = sum_s c[r][s] * x[s][d] — streams x exactly once
__global__ __launch_bounds__(256) void gmat_kernel(const float* __restrict__ x,
                                                   const float* __restrict__ c,
                                                   float* __restrict__ g) {
    const int wave = threadIdx.x >> 6;
    const int lane = threadIdx.x & 63;
    const int gw = blockIdx.x * 4 + wave;
    const int nw = gridDim.x * 4;
    float4 a0 = {0, 0, 0, 0}, a1 = {0, 0, 0, 0}, a2 = {0, 0, 0, 0},
           a3 = {0, 0, 0, 0}, a4 = {0, 0, 0, 0};
    for (int s = gw; s < NN; s += nw) {
        float4 v = ((const float4*)(x + (size_t)s * DD))[lane];
        float c0 = c[0 * NN + s], c1 = c[1 * NN + s], c2 = c[2 * NN + s],
              c3 = c[3 * NN + s], c4 = c[4 * NN + s];
        a0.x += c0 * v.x; a0.y += c0 * v.y; a0.z += c0 * v.z; a0.w += c0 * v.w;
        a1.x += c1 * v.x; a1.y += c1 * v.y; a1.z += c1 * v.z; a1.w += c1 * v.w;
        a2.x += c2 * v.x; a2.y += c2 * v.y; a2.z += c2 * v.z; a2.w += c2 * v.w;
        a3.x += c3 * v.x; a3.y += c3 * v.y; a3.z += c3 * v.z; a3.w += c3 * v.w;
        a4.x += c4 * v.x; a4.y += c4 * v.y; a4.z += c4 * v.z; a4.w += c4 * v.w;
    }
    float4 acc[5] = {a0, a1, a2, a3, a4};
    #pragma unroll
    for (int r = 0; r < RR; ++r) {
        float* gr = g + r * DD + lane * 4;
        unsafeAtomicAdd(gr + 0, acc[r].x);
        unsafeAtomicAdd(gr + 1, acc[r].y);
        unsafeAtomicAdd(gr + 2, acc[r].z);
        unsafeAtomicAdd(gr + 3, acc[r].w);
    }
}

__global__ __launch_bounds__(64) void mlp_kernel(const float* __restrict__ gsum,
                                                 const float* __restrict__ W1,
                                                 const float* __restrict__ b1,
                                                 const float* __restrict__ gamma,
                                                 const float* __restrict__ beta,
                                                 const float* __restrict__ W2,
                                                 const float* __restrict__ b2,
                                                 const float* __restrict__ attn_bias,
                                                 float* __restrict__ w) {
    const int t = threadIdx.x;
    __shared__ float gs[DD];
    const float invN = 1.0f / (float)NN;
    for (int r = 0; r < RR; ++r) {
        for (int d = t; d < DD; d += 64) gs[d] = gsum[r * DD + d] * invN;
        __syncthreads();
        float h = b1[t];
        for (int d = 0; d < DD; ++d) h += gs[d] * W1[d * HH + t];
        float mu = h;
        #pragma unroll
        for (int o = 32; o; o >>= 1) mu += __shfl_xor(mu, o, 64);
        mu *= (1.0f / 64.0f);
        float cc = h - mu;
        float var = cc * cc;
        #pragma unroll
        for (int o = 32; o; o >>= 1) var += __shfl_xor(var, o, 64);
        var *= (1.0f / 64.0f);
        float hn = cc * rsqrtf(var + 1e-5f) * gamma[t] + beta[t];
        hn = fmaxf(hn, 0.0f);
        float sc = hn * W2[t];
        #pragma unroll
        for (int o = 32; o; o >>= 1) sc += __shfl_xor(sc, o, 64);
        if (t == 0) {
            float s = sc + b2[0] + attn_bias[r];
            float ww = 2.0f / (1.0f + expf(-s * 0.5f));
            ww = fminf(fmaxf(ww, 0.05f), 2.0f);
            w[r] = ww;
        }
        __syncthreads();
    }
}

__global__ __launch_bounds__(256) void xcvt_kernel(const float* __restrict__ x,
                                                   ushort4* __restrict__ xh) {
    int i = blockIdx.x * 256 + threadIdx.x;
    if (i < NN * DD / 4) {
        float4 v = ((const float4*)x)[i];
        ushort4 q;
        q.x = bf16rn(v.x); q.y = bf16rn(v.y); q.z = bf16rn(v.z); q.w = bf16rn(v.w);
        xh[i] = q;
    }
}

__device__ inline float4 bf16row(const ushort4* __restrict__ xh, int s, int lane) {
    ushort4 q = xh[(size_t)s * (DD / 4) + lane];
    float4 v;
    v.x = __uint_as_float((unsigned)q.x << 16);
    v.y = __uint_as_float((unsigned)q.y << 16);
    v.z = __uint_as_float((unsigned)q.z << 16);
    v.w = __uint_as_float((unsigned)q.w << 16);
    return v;
}

// NEW pull: one wave per node, contiguous d-major ushort buckets
__global__ __launch_bounds__(256) void out_pull2_kernel(const ushort4* __restrict__ xh,
                                                        const unsigned short* __restrict__ esrc,
                                                        const int* __restrict__ off,
                                                        const int* __restrict__ endv,
                                                        const float* __restrict__ invc,
                                                        const float* __restrict__ w,
                                                        float* __restrict__ out) {
    const int node = blockIdx.x * 4 + (threadIdx.x >> 6);
    if (node >= NN) return;
    const int lane = threadIdx.x & 63;

    float4 acc = {0, 0, 0, 0};
    #pragma unroll
    for (int r = 0; r < RR; ++r) {
        const int b = __builtin_amdgcn_readfirstlane(off[node * RR + r]);
        const int e_ = __builtin_amdgcn_readfirstlane(endv[node * RR + r]);
        const float coef = w[r] * invc[r * NN + node];
        float4 t = {0, 0, 0, 0};
        int e = b;
        for (; e + 4 <= e_; e += 4) {
            int s0 = __builtin_amdgcn_readfirstlane((int)esrc[e + 0]);
            int s1 = __builtin_amdgcn_readfirstlane((int)esrc[e + 1]);
            int s2 = __builtin_amdgcn_readfirstlane((int)esrc[e + 2]);
            int s3 = __builtin_amdgcn_readfirstlane((int)esrc[e + 3]);
            float4 v0 = bf16row(xh, s0, lane);
            float4 v1 = bf16row(xh, s1, lane);
            float4 v2 = bf16row(xh, s2, lane);
            float4 v3 = bf16row(xh, s3, lane);
            t.x += (v0.x + v1.x) + (v2.x + v3.x);
            t.y += (v0.y + v1.y) + (v2.y + v3.y);
            t.z += (v0.z + v1.z) + (v2.z + v3.z);
            t.w += (v0.w + v1.w) + (v2.w + v3.w);
        }
        for (; e < e_; ++e) {
            int s = __builtin_amdgcn_readfirstlane((int)esrc[e]);
            float4 v = bf16row(xh, s, lane);
            t.x += v.x; t.y += v.y; t.z += v.z; t.w += v.w;
        }
        acc.x += coef * t.x; acc.y += coef * t.y;
        acc.z += coef * t.z; acc.w += coef * t.w;
    }
    ((float4*)(out + (size_t)node * DD))[lane] = acc;
}

// ---------------- fallback kernels (rounds 2/4, unchanged) ----------------
__global__ __launch_bounds__(256) void off_kernel(int* cnt, int* __restrict__ off,
                                                  int* __restrict__ cur,
                                                  int* __restrict__ ctr, float* invc) {
    int i = blockIdx.x * 256 + threadIdx.x;
    if (i < RN) {
        int cv = cnt[i];
        int o = atomicAdd(ctr, cv);
        off[i] = o;
        cur[i] = o;
        invc[i] = (cv > 0) ? (1.0f / (float)cv) : 0.0f;
    }
}

template <bool WITH_C>
__global__ __launch_bounds__(256) void fill_kernel(const int* __restrict__ src,
                                                   const int* __restrict__ dst,
                                                   int* __restrict__ cur,
                                                   int* __restrict__ esrc,
                                                   const float* __restrict__ invc,
                                                   float* __restrict__ c) {
    int i = blockIdx.x * 256 + threadIdx.x;
    if (i < RR * EE) {
        int r = i / EE;
        int d = dst[i];
        int s = src[i];
        int slot = atomicAdd(&cur[r * NN + d], 1);
        esrc[slot] = s;
        if constexpr (WITH_C) {
            unsafeAtomicAdd(&c[r * NN + s], invc[r * NN + d]);
        }
    }
}

__global__ __launch_bounds__(256) void g_kernel(const float* __restrict__ x,
                                                const int* __restrict__ src,
                                                const int* __restrict__ dst,
                                                const float* __restrict__ invc,
                                                float* __restrict__ g) {
    const int r = blockIdx.y;
    const int wave = threadIdx.x >> 6;
    const int lane = threadIdx.x & 63;
    const int gw = blockIdx.x * 4 + wave;
    const int nw = gridDim.x * 4;
    const int* __restrict__ srcR = src + r * EE;
    const int* __restrict__ dstR = dst + r * EE;
    const float* __restrict__ invcR = invc + r * NN;
    float4 acc = {0, 0, 0, 0};
    for (int e = gw; e < EE; e += nw) {
        int eu = __builtin_amdgcn_readfirstlane(e);
        int s = srcR[eu];
        int dn = dstR[eu];
        float ic = invcR[dn];
        float4 v = ((const float4*)(x + (size_t)s * DD))[lane];
        acc.x += v.x * ic; acc.y += v.y * ic; acc.z += v.z * ic; acc.w += v.w * ic;
    }
    float* gr = g + r * DD + lane * 4;
    unsafeAtomicAdd(gr + 0, acc.x);
    unsafeAtomicAdd(gr + 1, acc.y);
    unsafeAtomicAdd(gr + 2, acc.z);
    unsafeAtomicAdd(gr + 3, acc.w);
}

template <bool BF16>
__device__ inline float4 loadrow(const float* __restrict__ x,
                                 const ushort4* __restrict__ xh, int s, int lane) {
    if constexpr (BF16) {
        return bf16row(xh, s, lane);
    } else {
        return ((const float4*)(x + (size_t)s * DD))[lane];
    }
}

template <bool BF16>
__global__ __launch_bounds__(256) void out_pull_kernel(const float* __restrict__ x,
                                                       const ushort4* __restrict__ xh,
                                                       const int* __restrict__ esrc,
                                                       const int* __restrict__ off,
                                                       const int* __restrict__ endv,
                                                       const float* __restrict__ invc,
                                                       const float* __restrict__ w,
                                                       float* __restrict__ out) {
    const int node = blockIdx.x * 4 + (threadIdx.x >> 6);
    if (node >= NN) return;
    const int lane = threadIdx.x & 63;

    float4 acc = {0, 0, 0, 0};
    #pragma unroll
    for (int r = 0; r < RR; ++r) {
        const int idx = r * NN + node;
        const int b = __builtin_amdgcn_readfirstlane(off[idx]);
        const int e_ = __builtin_amdgcn_readfirstlane(endv[idx]);
        const float coef = w[r] * invc[idx];
        float4 t = {0, 0, 0, 0};
        int e = b;
        for (; e + 4 <= e_; e += 4) {
            int s0 = __builtin_amdgcn_readfirstlane(esrc[e + 0]);
            int s1 = __builtin_amdgcn_readfirstlane(esrc[e + 1]);
            int s2 = __builtin_amdgcn_readfirstlane(esrc[e + 2]);
            int s3 = __builtin_amdgcn_readfirstlane(esrc[e + 3]);
            float4 v0 = loadrow<BF16>(x, xh, s0, lane);
            float4 v1 = loadrow<BF16>(x, xh, s1, lane);
            float4 v2 = loadrow<BF16>(x, xh, s2, lane);
            float4 v3 = loadrow<BF16>(x, xh, s3, lane);
            t.x += (v0.x + v1.x) + (v2.x + v3.x);
            t.y += (v0.y + v1.y) + (v2.y + v3.y);
            t.z += (v0.z + v1.z) + (v2.z + v3.z);
            t.w += (v0.w + v1.w) + (v2.w + v3.w);
        }
        for (; e < e_; ++e) {
            int s = __builtin_amdgcn_readfirstlane(esrc[e]);
            float4 v = loadrow<BF16>(x, xh, s, lane);
            t.x += v.x; t.y += v.y; t.z += v.z; t.w += v.w;
        }
        acc.x += coef * t.x; acc.y += coef * t.y;
        acc.z += coef * t.z; acc.w += coef * t.w;
    }
    ((float4*)(out + (size_t)node * DD))[lane] = acc;
}

__global__ __launch_bounds__(256) void invcnt_kernel(float* __restrict__ c) {
    int i = blockIdx.x * 256 + threadIdx.x;
    if (i < RN) {
        int v = ((const int*)c)[i];
        c[i] = (v > 0) ? (1.0f / (float)v) : 0.0f;
    }
}

__global__ __launch_bounds__(256) void out_scatter_kernel(const float* __restrict__ x,
                                                          const int* __restrict__ src,
                                                          const int* __restrict__ dst,
                                                          const float* __restrict__ invc,
                                                          const float* __restrict__ w,
                                                          float* __restrict__ out) {
    const int r = blockIdx.y;
    const float wr = w[r];
    const int wave = threadIdx.x >> 6;
    const int lane = threadIdx.x & 63;
    const int gw = blockIdx.x * 4 + wave;
    const int nw = gridDim.x * 4;
    const int* __restrict__ srcR = src + r * EE;
    const int* __restrict__ dstR = dst + r * EE;
    const float* __restrict__ invcR = invc + r * NN;
    for (int e = gw; e < EE; e += nw) {
        int eu = __builtin_amdgcn_readfirstlane(e);
        int s = srcR[eu];
        int dn = dstR[eu];
        float coef = wr * invcR[dn];
        float4 v = ((const float4*)(x + (size_t)s * DD))[lane];
        float* o = out + (size_t)dn * DD + lane * 4;
        unsafeAtomicAdd(o + 0, v.x * coef);
        unsafeAtomicAdd(o + 1, v.y * coef);
        unsafeAtomicAdd(o + 2, v.z * coef);
        unsafeAtomicAdd(o + 3, v.w * coef);
    }
}

extern "C" void kernel_launch(void* const* d_in, const int* in_sizes, int n_in,
                              void* d_out, int out_size, void* d_ws, size_t ws_size,
                              hipStream_t stream) {
    const float* x = (const float*)d_in[0];
    const int* src = (const int*)d_in[1];
    const int* dst = (const int*)d_in[2];
    const float* W1 = (const float*)d_in[3];
    const float* b1 = (const float*)d_in[4];
    const float* gamma = (const float*)d_in[5];
    const float* beta = (const float*)d_in[6];
    const float* W2 = (const float*)d_in[7];
    const float* b2 = (const float*)d_in[8];
    const float* attn_bias = (const float*)d_in[9];
    float* out = (float*)d_out;
    float* ws = (float*)d_ws;

    const int EDGE_GRID = (RR * EE + 255) / 256;
    const int RN_GRID = (RN + 255) / 256;

    if (ws_size >= BYTES_NEW) {
        // ---- d-major ushort CSR + range-blocked fill ----
        int* cnt = (int*)ws;
        float* invc = ws;
        int* off = (int*)ws + P_OFF;
        int* cur = (int*)ws + P_CUR;
        float* c = ws + P_C;
        float* g = ws + P_G;
        float* w = ws + P_W;
        int* bsum = (int*)ws + P_BSUM;
        int* bbase = (int*)ws + P_BBASE;
        unsigned short* esrc = (unsigned short*)((int*)ws + P_ESRC);
        ushort4* xh = (ushort4*)((int*)ws + P_XH);

        hipMemsetAsync(cnt, 0, (size_t)RN * 4, stream);
        hipMemsetAsync(c, 0, (size_t)(RN + 1288) * 4, stream);  // c, g, w

        xcvt_kernel<<<(NN * DD / 4 + 255) / 256, 256, 0, stream>>>(x, xh);
        deg_kernel<<<EDGE_GRID, 256, 0, stream>>>(dst, cnt);
        bsum_kernel<<<NBLK, 256, 0, stream>>>(cnt, bsum);
        bscan_kernel<<<1, 64, 0, stream>>>(bsum, bbase);
        off2_kernel<<<NBLK, 256, 0, stream>>>(cnt, bbase, off, cur);
        fill2_kernel<<<EDGE_GRID, 256, 0, stream>>>(src, dst, cur, esrc, invc, c,
                                                    0, NN / 2);
        fill2_kernel<<<EDGE_GRID, 256, 0, stream>>>(src, dst, cur, esrc, invc, c,
                                                    NN / 2, NN);
        gmat_kernel<<<128, 256, 0, stream>>>(x, c, g);
        mlp_kernel<<<1, 64, 0, stream>>>(g, W1, b1, gamma, beta, W2, b2, attn_bias, w);
        out_pull2_kernel<<<(NN + 3) / 4, 256, 0, stream>>>(xh, esrc, off, cur, invc,
                                                           w, out);
    } else if (ws_size >= BYTES_F32) {
        const bool bf16 = (ws_size >= BYTES_BF16);
        int* cnt = (int*)ws;
        float* invc = ws;
        int* off = (int*)ws + F_OFF;
        int* cur = (int*)ws + F_CUR;
        float* c = ws + F_C;
        float* g = ws + F_G;
        float* w = ws + F_W;
        int* ctr = (int*)ws + F_CTR;
        int* esrc = (int*)ws + F_ESRC;
        ushort4* xh = (ushort4*)((int*)ws + F_XH);

        hipMemsetAsync(cnt, 0, (size_t)RN * 4, stream);
        hipMemsetAsync(c, 0, (size_t)(RN + 1296) * 4, stream);

        if (bf16)
            xcvt_kernel<<<(NN * DD / 4 + 255) / 256, 256, 0, stream>>>(x, xh);
        deg_kernel<<<EDGE_GRID, 256, 0, stream>>>(dst, cnt);
        off_kernel<<<RN_GRID, 256, 0, stream>>>(cnt, off, cur, ctr, invc);
        fill_kernel<true><<<EDGE_GRID, 256, 0, stream>>>(src, dst, cur, esrc, invc, c);
        gmat_kernel<<<128, 256, 0, stream>>>(x, c, g);
        mlp_kernel<<<1, 64, 0, stream>>>(g, W1, b1, gamma, beta, W2, b2, attn_bias, w);
        if (bf16)
            out_pull_kernel<true><<<(NN + 3) / 4, 256, 0, stream>>>(x, xh, esrc, off,
                                                                    cur, invc, w, out);
        else
            out_pull_kernel<false><<<(NN + 3) / 4, 256, 0, stream>>>(x, xh, esrc, off,
                                                                     cur, invc, w, out);
    } else if (ws_size >= BYTES_CSR2) {
        int* cnt = (int*)ws;
        float* invc = ws;
        int* off = (int*)ws + C2_OFF;
        int* cur = (int*)ws + C2_CUR;
        float* g = ws + C2_G;
        float* w = ws + C2_W;
        int* ctr = (int*)ws + C2_CTR;
        int* esrc = (int*)ws + C2_ESRC;

        hipMemsetAsync(cnt, 0, (size_t)RN * 4, stream);
        hipMemsetAsync(g, 0, (size_t)1296 * 4, stream);

        deg_kernel<<<EDGE_GRID, 256, 0, stream>>>(dst, cnt);
        off_kernel<<<RN_GRID, 256, 0, stream>>>(cnt, off, cur, ctr, invc);
        fill_kernel<false><<<EDGE_GRID, 256, 0, stream>>>(src, dst, cur, esrc, invc,
                                                          nullptr);
        g_kernel<<<dim3(512, RR), 256, 0, stream>>>(x, src, dst, invc, g);
        mlp_kernel<<<1, 64, 0, stream>>>(g, W1, b1, gamma, beta, W2, b2, attn_bias, w);
        out_pull_kernel<false><<<(NN + 3) / 4, 256, 0, stream>>>(x, nullptr, esrc, off,
                                                                 cur, invc, w, out);
    } else {
        float* cnt = ws;
        float* g = ws + RN;
        float* w = ws + RN + RR * DD;
        hipMemsetAsync(ws, 0, (size_t)(RN + RR * DD + RR) * 4, stream);
        hipMemsetAsync(d_out, 0, (size_t)NN * DD * 4, stream);
        deg_kernel<<<EDGE_GRID, 256, 0, stream>>>(dst, (int*)cnt);
        invcnt_kernel<<<RN_GRID, 256, 0, stream>>>(cnt);
        g_kernel<<<dim3(512, RR), 256, 0, stream>>>(x, src, dst, cnt, g);
        mlp_kernel<<<1, 64, 0, stream>>>(g, W1, b1, gamma, beta, W2, b2, attn_bias, w);
        out_scatter_kernel<<<dim3(512, RR), 256, 0, stream>>>(x, src, dst, cnt, w, out);
    }
}